// Round 1
// baseline (4547.771 us; speedup 1.0000x reference)
//
#include <hip/hip_runtime.h>
#include <hip/hip_bf16.h>

#define IN_DIM 256
#define HIDDEN 256
#define EMBED 128

// ---------------------------------------------------------------------------
// GEMM: C[M,N] = A[M,K] @ W^T + bias, W is [N,K] row-major (torch Linear).
// BM=64, BN=64, BK=16, 256 threads, 4x4 micro-tile.
// LDS tiles stored transposed (Ast[k][m], Wst[k][n]) so the inner loop reads
// two ds_read_b128 per k (compute-bound: 16 FMA vs 2 b128 reads).
// ---------------------------------------------------------------------------
__global__ __launch_bounds__(256) void gemm_bt(
    const float* __restrict__ A, const float* __restrict__ W,
    const float* __restrict__ bias, float* __restrict__ C,
    int M, int N, int K)
{
    __shared__ float Ast[16][68];   // [k][m], pad to 68 (2-way conflicts only)
    __shared__ float Wst[16][68];   // [k][n]
    const int tid = threadIdx.x;
    const int tx = tid & 15, ty = tid >> 4;
    const int m0 = blockIdx.x * 64, n0 = blockIdx.y * 64;

    const int lm = tid >> 2;         // 0..63  (row within tile)
    const int lk = (tid & 3) << 2;   // 0,4,8,12

    float acc[4][4] = {};

    for (int k0 = 0; k0 < K; k0 += 16) {
        float4 av = make_float4(0.f, 0.f, 0.f, 0.f);
        const int am = m0 + lm;
        if (am < M) av = *(const float4*)&A[(size_t)am * K + k0 + lk];
        const float4 wv = *(const float4*)&W[(size_t)(n0 + lm) * K + k0 + lk];
        __syncthreads();   // previous iteration's reads done
        Ast[lk + 0][lm] = av.x; Ast[lk + 1][lm] = av.y;
        Ast[lk + 2][lm] = av.z; Ast[lk + 3][lm] = av.w;
        Wst[lk + 0][lm] = wv.x; Wst[lk + 1][lm] = wv.y;
        Wst[lk + 2][lm] = wv.z; Wst[lk + 3][lm] = wv.w;
        __syncthreads();
#pragma unroll
        for (int k = 0; k < 16; ++k) {
            const float4 a = *(const float4*)&Ast[k][ty * 4];
            const float4 b = *(const float4*)&Wst[k][tx * 4];
            acc[0][0] += a.x * b.x; acc[0][1] += a.x * b.y; acc[0][2] += a.x * b.z; acc[0][3] += a.x * b.w;
            acc[1][0] += a.y * b.x; acc[1][1] += a.y * b.y; acc[1][2] += a.y * b.z; acc[1][3] += a.y * b.w;
            acc[2][0] += a.z * b.x; acc[2][1] += a.z * b.y; acc[2][2] += a.z * b.z; acc[2][3] += a.z * b.w;
            acc[3][0] += a.w * b.x; acc[3][1] += a.w * b.y; acc[3][2] += a.w * b.z; acc[3][3] += a.w * b.w;
        }
    }

    const float4 bv = *(const float4*)&bias[n0 + tx * 4];
#pragma unroll
    for (int i = 0; i < 4; ++i) {
        const int m = m0 + ty * 4 + i;
        if (m < M) {
            float4 o;
            o.x = acc[i][0] + bv.x; o.y = acc[i][1] + bv.y;
            o.z = acc[i][2] + bv.z; o.w = acc[i][3] + bv.w;
            *(float4*)&C[(size_t)m * N + n0 + tx * 4] = o;
        }
    }
}

// ---------------------------------------------------------------------------
// GEMM: C[M,N] = A[M,K] @ B[K,N]  (no transpose, no bias) — for U = emb @ W_u
// ---------------------------------------------------------------------------
__global__ __launch_bounds__(256) void gemm_nn(
    const float* __restrict__ A, const float* __restrict__ B,
    float* __restrict__ C, int M, int N, int K)
{
    __shared__ float Ast[16][68];   // [k][m]
    __shared__ float Bs[16][68];    // [k][n]
    const int tid = threadIdx.x;
    const int tx = tid & 15, ty = tid >> 4;
    const int m0 = blockIdx.x * 64, n0 = blockIdx.y * 64;

    const int lm = tid >> 2;
    const int lk = (tid & 3) << 2;
    const int bk = tid >> 4;          // 0..15
    const int bn = (tid & 15) << 2;   // 0..60

    float acc[4][4] = {};

    for (int k0 = 0; k0 < K; k0 += 16) {
        float4 av = make_float4(0.f, 0.f, 0.f, 0.f);
        const int am = m0 + lm;
        if (am < M) av = *(const float4*)&A[(size_t)am * K + k0 + lk];
        const float4 bvl = *(const float4*)&B[(size_t)(k0 + bk) * N + n0 + bn];
        __syncthreads();
        Ast[lk + 0][lm] = av.x; Ast[lk + 1][lm] = av.y;
        Ast[lk + 2][lm] = av.z; Ast[lk + 3][lm] = av.w;
        *(float4*)&Bs[bk][bn] = bvl;
        __syncthreads();
#pragma unroll
        for (int k = 0; k < 16; ++k) {
            const float4 a = *(const float4*)&Ast[k][ty * 4];
            const float4 b = *(const float4*)&Bs[k][tx * 4];
            acc[0][0] += a.x * b.x; acc[0][1] += a.x * b.y; acc[0][2] += a.x * b.z; acc[0][3] += a.x * b.w;
            acc[1][0] += a.y * b.x; acc[1][1] += a.y * b.y; acc[1][2] += a.y * b.z; acc[1][3] += a.y * b.w;
            acc[2][0] += a.z * b.x; acc[2][1] += a.z * b.y; acc[2][2] += a.z * b.z; acc[2][3] += a.z * b.w;
            acc[3][0] += a.w * b.x; acc[3][1] += a.w * b.y; acc[3][2] += a.w * b.z; acc[3][3] += a.w * b.w;
        }
    }

#pragma unroll
    for (int i = 0; i < 4; ++i) {
        const int m = m0 + ty * 4 + i;
        if (m < M) {
            float4 o;
            o.x = acc[i][0]; o.y = acc[i][1]; o.z = acc[i][2]; o.w = acc[i][3];
            *(float4*)&C[(size_t)m * N + n0 + tx * 4] = o;
        }
    }
}

// ---------------------------------------------------------------------------
// Finsler edge weight, one wave (64 lanes) per edge. EMBED=128 -> 2 elems/lane.
// w_e = exp(-clip(alpha) * max(||xi-xj|| + tanh(xj.w_beta) * <xi-xj, U[src]>, 0))
// ---------------------------------------------------------------------------
__global__ __launch_bounds__(256) void edge_weight(
    const float* __restrict__ emb, const float* __restrict__ U,
    const float* __restrict__ w_beta, const float* __restrict__ alpha_p,
    const int* __restrict__ src, const int* __restrict__ dst,
    float* __restrict__ w_out, int E)
{
    const int wv = (int)((blockIdx.x * (size_t)blockDim.x + threadIdx.x) >> 6);
    const int lane = threadIdx.x & 63;
    if (wv >= E) return;
    const int s = src[wv], d = dst[wv];

    const float* xj = emb + (size_t)s * EMBED;
    const float* xi = emb + (size_t)d * EMBED;
    const float* uj = U + (size_t)s * EMBED;

    const float xj0 = xj[lane], xj1 = xj[lane + 64];
    const float xi0 = xi[lane], xi1 = xi[lane + 64];
    const float u0 = uj[lane],  u1 = uj[lane + 64];
    const float wb0 = w_beta[lane], wb1 = w_beta[lane + 64];

    const float d0 = xi0 - xj0, d1 = xi1 - xj1;
    float pe = d0 * d0 + d1 * d1;        // euclid^2 partial
    float pa = d0 * u0 + d1 * u1;        // asym partial
    float pb = xj0 * wb0 + xj1 * wb1;    // beta dot partial

#pragma unroll
    for (int off = 32; off > 0; off >>= 1) {
        pe += __shfl_xor(pe, off);
        pa += __shfl_xor(pa, off);
        pb += __shfl_xor(pb, off);
    }

    if (lane == 0) {
        const float alpha = fminf(fmaxf(alpha_p[0], 0.1f), 10.0f);
        const float beta = tanhf(pb);
        const float dist = sqrtf(pe) + beta * pa;
        w_out[wv] = expf(-alpha * fmaxf(dist, 0.0f));
    }
}

// ---------------------------------------------------------------------------
// Scatter: out[dst] += H[src] * w, one wave per edge, 4 cols/lane (float4 read,
// 4 scalar fp32 global atomics).
// ---------------------------------------------------------------------------
__global__ __launch_bounds__(256) void edge_scatter(
    const float* __restrict__ H, const float* __restrict__ w,
    const int* __restrict__ src, const int* __restrict__ dst,
    float* __restrict__ out, int E)
{
    const int wv = (int)((blockIdx.x * (size_t)blockDim.x + threadIdx.x) >> 6);
    const int lane = threadIdx.x & 63;
    if (wv >= E) return;
    const int s = src[wv], d = dst[wv];
    const float we = w[wv];

    const float4 v = *(const float4*)&H[(size_t)s * HIDDEN + lane * 4];
    float* o = out + (size_t)d * HIDDEN + lane * 4;
    atomicAdd(o + 0, v.x * we);
    atomicAdd(o + 1, v.y * we);
    atomicAdd(o + 2, v.z * we);
    atomicAdd(o + 3, v.w * we);
}

// ---------------------------------------------------------------------------
__global__ __launch_bounds__(256) void relu_inplace(float* __restrict__ out, int n4)
{
    const int i = blockIdx.x * blockDim.x + threadIdx.x;
    if (i < n4) {
        float4 v = ((float4*)out)[i];
        v.x = fmaxf(v.x, 0.f); v.y = fmaxf(v.y, 0.f);
        v.z = fmaxf(v.z, 0.f); v.w = fmaxf(v.w, 0.f);
        ((float4*)out)[i] = v;
    }
}

// ---------------------------------------------------------------------------
extern "C" void kernel_launch(void* const* d_in, const int* in_sizes, int n_in,
                              void* d_out, int out_size, void* d_ws, size_t ws_size,
                              hipStream_t stream)
{
    const float* h        = (const float*)d_in[0];
    const int*   pos_src  = (const int*)d_in[1];
    const int*   pos_dst  = (const int*)d_in[2];
    const int*   neg_src  = (const int*)d_in[3];
    const int*   neg_dst  = (const int*)d_in[4];
    const float* emb      = (const float*)d_in[5];
    const float* W_pos    = (const float*)d_in[6];
    const float* b_pos    = (const float*)d_in[7];
    const float* W_neg    = (const float*)d_in[8];
    const float* b_neg    = (const float*)d_in[9];
    const float* W_self   = (const float*)d_in[10];
    const float* b_self   = (const float*)d_in[11];
    const float* w_pos_b  = (const float*)d_in[12];
    const float* W_pos_u  = (const float*)d_in[13];
    const float* alpha_p  = (const float*)d_in[14];
    const float* w_neg_b  = (const float*)d_in[15];
    const float* W_neg_u  = (const float*)d_in[16];
    const float* alpha_n  = (const float*)d_in[17];
    float* out = (float*)d_out;

    const int n_nodes = in_sizes[0] / IN_DIM;   // 100000
    const int E       = in_sizes[1];            // 500000

    // Workspace layout (floats). U and H overlap (disjoint lifetimes).
    float* ws    = (float*)d_ws;
    float* wpos  = ws;                       // [E]
    float* wneg  = ws + E;                   // [E]
    float* Ubuf  = ws + 2 * (size_t)E;       // [n_nodes * EMBED]   (phase 1)
    float* Hbuf  = ws + 2 * (size_t)E;       // [n_nodes * HIDDEN]  (phase 2)

    const dim3 blk(256);
    const dim3 gU((n_nodes + 63) / 64, EMBED / 64);    // U GEMMs
    const dim3 gH((n_nodes + 63) / 64, HIDDEN / 64);   // H GEMMs
    const dim3 gE((E + 3) / 4);                        // wave-per-edge kernels

    // --- Phase 1: edge weights ---
    gemm_nn<<<gU, blk, 0, stream>>>(emb, W_pos_u, Ubuf, n_nodes, EMBED, EMBED);
    edge_weight<<<gE, blk, 0, stream>>>(emb, Ubuf, w_pos_b, alpha_p,
                                        pos_src, pos_dst, wpos, E);
    gemm_nn<<<gU, blk, 0, stream>>>(emb, W_neg_u, Ubuf, n_nodes, EMBED, EMBED);
    edge_weight<<<gE, blk, 0, stream>>>(emb, Ubuf, w_neg_b, alpha_n,
                                        neg_src, neg_dst, wneg, E);

    // --- Phase 2: self message directly into out, then scatter pos/neg ---
    gemm_bt<<<gH, blk, 0, stream>>>(h, W_self, b_self, out, n_nodes, HIDDEN, IN_DIM);

    gemm_bt<<<gH, blk, 0, stream>>>(h, W_pos, b_pos, Hbuf, n_nodes, HIDDEN, IN_DIM);
    edge_scatter<<<gE, blk, 0, stream>>>(Hbuf, wpos, pos_src, pos_dst, out, E);

    gemm_bt<<<gH, blk, 0, stream>>>(h, W_neg, b_neg, Hbuf, n_nodes, HIDDEN, IN_DIM);
    edge_scatter<<<gE, blk, 0, stream>>>(Hbuf, wneg, neg_src, neg_dst, out, E);

    // --- Phase 3: ReLU ---
    const int n4 = n_nodes * HIDDEN / 4;
    relu_inplace<<<(n4 + 255) / 256, blk, 0, stream>>>(out, n4);
}

// Round 2
// 1478.695 us; speedup vs baseline: 3.0755x; 3.0755x over previous
//
#include <hip/hip_runtime.h>
#include <hip/hip_bf16.h>
#include <stdint.h>

#define IN_DIM 256
#define HIDDEN 256
#define EMBED 128

// ---------------------------------------------------------------------------
// GEMM: C[M,N] = A[M,K] @ W^T + bias, W is [N,K] row-major (torch Linear).
// BM=64, BN=64, BK=16, 256 threads, 4x4 micro-tile.
// ---------------------------------------------------------------------------
__global__ __launch_bounds__(256) void gemm_bt(
    const float* __restrict__ A, const float* __restrict__ W,
    const float* __restrict__ bias, float* __restrict__ C,
    int M, int N, int K)
{
    __shared__ float Ast[16][68];   // [k][m]
    __shared__ float Wst[16][68];   // [k][n]
    const int tid = threadIdx.x;
    const int tx = tid & 15, ty = tid >> 4;
    const int m0 = blockIdx.x * 64, n0 = blockIdx.y * 64;

    const int lm = tid >> 2;         // 0..63
    const int lk = (tid & 3) << 2;   // 0,4,8,12

    float acc[4][4] = {};

    for (int k0 = 0; k0 < K; k0 += 16) {
        float4 av = make_float4(0.f, 0.f, 0.f, 0.f);
        const int am = m0 + lm;
        if (am < M) av = *(const float4*)&A[(size_t)am * K + k0 + lk];
        const float4 wv = *(const float4*)&W[(size_t)(n0 + lm) * K + k0 + lk];
        __syncthreads();
        Ast[lk + 0][lm] = av.x; Ast[lk + 1][lm] = av.y;
        Ast[lk + 2][lm] = av.z; Ast[lk + 3][lm] = av.w;
        Wst[lk + 0][lm] = wv.x; Wst[lk + 1][lm] = wv.y;
        Wst[lk + 2][lm] = wv.z; Wst[lk + 3][lm] = wv.w;
        __syncthreads();
#pragma unroll
        for (int k = 0; k < 16; ++k) {
            const float4 a = *(const float4*)&Ast[k][ty * 4];
            const float4 b = *(const float4*)&Wst[k][tx * 4];
            acc[0][0] += a.x * b.x; acc[0][1] += a.x * b.y; acc[0][2] += a.x * b.z; acc[0][3] += a.x * b.w;
            acc[1][0] += a.y * b.x; acc[1][1] += a.y * b.y; acc[1][2] += a.y * b.z; acc[1][3] += a.y * b.w;
            acc[2][0] += a.z * b.x; acc[2][1] += a.z * b.y; acc[2][2] += a.z * b.z; acc[2][3] += a.z * b.w;
            acc[3][0] += a.w * b.x; acc[3][1] += a.w * b.y; acc[3][2] += a.w * b.z; acc[3][3] += a.w * b.w;
        }
    }

    const float4 bv = *(const float4*)&bias[n0 + tx * 4];
#pragma unroll
    for (int i = 0; i < 4; ++i) {
        const int m = m0 + ty * 4 + i;
        if (m < M) {
            float4 o;
            o.x = acc[i][0] + bv.x; o.y = acc[i][1] + bv.y;
            o.z = acc[i][2] + bv.z; o.w = acc[i][3] + bv.w;
            *(float4*)&C[(size_t)m * N + n0 + tx * 4] = o;
        }
    }
}

// ---------------------------------------------------------------------------
// GEMM: C[M,N] = A[M,K] @ B[K,N] (no transpose/bias) — U = emb @ W_u
// ---------------------------------------------------------------------------
__global__ __launch_bounds__(256) void gemm_nn(
    const float* __restrict__ A, const float* __restrict__ B,
    float* __restrict__ C, int M, int N, int K)
{
    __shared__ float Ast[16][68];
    __shared__ float Bs[16][68];
    const int tid = threadIdx.x;
    const int tx = tid & 15, ty = tid >> 4;
    const int m0 = blockIdx.x * 64, n0 = blockIdx.y * 64;

    const int lm = tid >> 2;
    const int lk = (tid & 3) << 2;
    const int bk = tid >> 4;
    const int bn = (tid & 15) << 2;

    float acc[4][4] = {};

    for (int k0 = 0; k0 < K; k0 += 16) {
        float4 av = make_float4(0.f, 0.f, 0.f, 0.f);
        const int am = m0 + lm;
        if (am < M) av = *(const float4*)&A[(size_t)am * K + k0 + lk];
        const float4 bvl = *(const float4*)&B[(size_t)(k0 + bk) * N + n0 + bn];
        __syncthreads();
        Ast[lk + 0][lm] = av.x; Ast[lk + 1][lm] = av.y;
        Ast[lk + 2][lm] = av.z; Ast[lk + 3][lm] = av.w;
        *(float4*)&Bs[bk][bn] = bvl;
        __syncthreads();
#pragma unroll
        for (int k = 0; k < 16; ++k) {
            const float4 a = *(const float4*)&Ast[k][ty * 4];
            const float4 b = *(const float4*)&Bs[k][tx * 4];
            acc[0][0] += a.x * b.x; acc[0][1] += a.x * b.y; acc[0][2] += a.x * b.z; acc[0][3] += a.x * b.w;
            acc[1][0] += a.y * b.x; acc[1][1] += a.y * b.y; acc[1][2] += a.y * b.z; acc[1][3] += a.y * b.w;
            acc[2][0] += a.z * b.x; acc[2][1] += a.z * b.y; acc[2][2] += a.z * b.z; acc[2][3] += a.z * b.w;
            acc[3][0] += a.w * b.x; acc[3][1] += a.w * b.y; acc[3][2] += a.w * b.z; acc[3][3] += a.w * b.w;
        }
    }

#pragma unroll
    for (int i = 0; i < 4; ++i) {
        const int m = m0 + ty * 4 + i;
        if (m < M) {
            float4 o;
            o.x = acc[i][0]; o.y = acc[i][1]; o.z = acc[i][2]; o.w = acc[i][3];
            *(float4*)&C[(size_t)m * N + n0 + tx * 4] = o;
        }
    }
}

// ---------------------------------------------------------------------------
// Finsler edge weight, one wave per edge.
// ---------------------------------------------------------------------------
__global__ __launch_bounds__(256) void edge_weight(
    const float* __restrict__ emb, const float* __restrict__ U,
    const float* __restrict__ w_beta, const float* __restrict__ alpha_p,
    const int* __restrict__ src, const int* __restrict__ dst,
    float* __restrict__ w_out, int E)
{
    const int wv = (int)((blockIdx.x * (size_t)blockDim.x + threadIdx.x) >> 6);
    const int lane = threadIdx.x & 63;
    if (wv >= E) return;
    const int s = src[wv], d = dst[wv];

    const float* xj = emb + (size_t)s * EMBED;
    const float* xi = emb + (size_t)d * EMBED;
    const float* uj = U + (size_t)s * EMBED;

    const float xj0 = xj[lane], xj1 = xj[lane + 64];
    const float xi0 = xi[lane], xi1 = xi[lane + 64];
    const float u0 = uj[lane],  u1 = uj[lane + 64];
    const float wb0 = w_beta[lane], wb1 = w_beta[lane + 64];

    const float d0 = xi0 - xj0, d1 = xi1 - xj1;
    float pe = d0 * d0 + d1 * d1;
    float pa = d0 * u0 + d1 * u1;
    float pb = xj0 * wb0 + xj1 * wb1;

#pragma unroll
    for (int off = 32; off > 0; off >>= 1) {
        pe += __shfl_xor(pe, off);
        pa += __shfl_xor(pa, off);
        pb += __shfl_xor(pb, off);
    }

    if (lane == 0) {
        const float alpha = fminf(fmaxf(alpha_p[0], 0.1f), 10.0f);
        const float beta = tanhf(pb);
        const float dist = sqrtf(pe) + beta * pa;
        w_out[wv] = expf(-alpha * fmaxf(dist, 0.0f));
    }
}

// ---------------------------------------------------------------------------
// CSR-by-dst build: zero -> hist -> scan(3 kernels) -> place
// ---------------------------------------------------------------------------
__global__ __launch_bounds__(256) void zero_int(int* __restrict__ p, int n)
{
    const int i = blockIdx.x * blockDim.x + threadIdx.x;
    if (i < n) p[i] = 0;
}

__global__ __launch_bounds__(256) void hist(
    const int* __restrict__ dst, int* __restrict__ counts, int E)
{
    const int e = blockIdx.x * blockDim.x + threadIdx.x;
    if (e < E) atomicAdd(&counts[dst[e]], 1);
}

// Per-block (1024 elems) exclusive scan; block totals to bsum.
__global__ __launch_bounds__(256) void scan1(
    const int* __restrict__ counts, int* __restrict__ offs,
    int* __restrict__ bsum, int n)
{
    __shared__ int wsum[4];
    const int t = threadIdx.x;
    const int gi = blockIdx.x * 1024 + t * 4;
    int v[4];
#pragma unroll
    for (int j = 0; j < 4; ++j) v[j] = (gi + j < n) ? counts[gi + j] : 0;
    const int local = v[0] + v[1] + v[2] + v[3];
    const int lane = t & 63;
    int x = local;
#pragma unroll
    for (int off = 1; off < 64; off <<= 1) {
        const int y = __shfl_up(x, off);
        if (lane >= off) x += y;
    }
    if (lane == 63) wsum[t >> 6] = x;
    __syncthreads();
    int woff = 0;
    const int wid = t >> 6;
    for (int w = 0; w < wid; ++w) woff += wsum[w];
    int run = woff + x - local;      // exclusive prefix within block
#pragma unroll
    for (int j = 0; j < 4; ++j) {
        if (gi + j < n) offs[gi + j] = run;
        run += v[j];
    }
    if (t == 255) bsum[blockIdx.x] = woff + x;   // block total
}

// Exclusive scan of <=128 block sums, one block.
__global__ __launch_bounds__(128) void scan2(int* __restrict__ bsum, int nb)
{
    __shared__ int tmp[128];
    const int t = threadIdx.x;
    tmp[t] = (t < nb) ? bsum[t] : 0;
    __syncthreads();
    if (t < nb) {
        int s = 0;
        for (int i = 0; i < t; ++i) s += tmp[i];
        bsum[t] = s;
    }
}

__global__ __launch_bounds__(256) void scan3(
    int* __restrict__ offs, int* __restrict__ cur,
    const int* __restrict__ bsum, int n, int E)
{
    const int gi = blockIdx.x * blockDim.x + threadIdx.x;
    if (gi < n) {
        const int v = offs[gi] + bsum[gi >> 10];
        offs[gi] = v;
        cur[gi] = v;
    }
    if (gi == 0) offs[n] = E;
}

// Permute (src, w) into dst-segment order.
__global__ __launch_bounds__(256) void place(
    const int* __restrict__ src, const int* __restrict__ dst,
    const float* __restrict__ w, int* __restrict__ cur,
    int* __restrict__ esrc, float* __restrict__ ew, int E)
{
    const int e = blockIdx.x * blockDim.x + threadIdx.x;
    if (e < E) {
        const int p = atomicAdd(&cur[dst[e]], 1);
        esrc[p] = src[e];
        ew[p] = w[e];
    }
}

// ---------------------------------------------------------------------------
// Deterministic gather: one wave per dst node, out[node] += sum_e w_e*H[src_e].
// RELU fuses the final activation into the last pass.
// ---------------------------------------------------------------------------
template <bool RELU>
__global__ __launch_bounds__(256) void gather(
    const float* __restrict__ H, const int* __restrict__ offs,
    const int* __restrict__ esrc, const float* __restrict__ ew,
    float* __restrict__ out, int n)
{
    const int node = (int)((blockIdx.x * (size_t)blockDim.x + threadIdx.x) >> 6);
    const int lane = threadIdx.x & 63;
    if (node >= n) return;
    const int s0 = offs[node], s1 = offs[node + 1];

    float4 acc = make_float4(0.f, 0.f, 0.f, 0.f);
    for (int k = s0; k < s1; ++k) {
        const int s = esrc[k];
        const float wv = ew[k];
        const float4 v = *(const float4*)&H[(size_t)s * HIDDEN + lane * 4];
        acc.x += v.x * wv; acc.y += v.y * wv;
        acc.z += v.z * wv; acc.w += v.w * wv;
    }

    float* o = out + (size_t)node * HIDDEN + lane * 4;
    float4 c = *(const float4*)o;
    c.x += acc.x; c.y += acc.y; c.z += acc.z; c.w += acc.w;
    if (RELU) {
        c.x = fmaxf(c.x, 0.f); c.y = fmaxf(c.y, 0.f);
        c.z = fmaxf(c.z, 0.f); c.w = fmaxf(c.w, 0.f);
    }
    *(float4*)o = c;
}

// ---------------------------------------------------------------------------
extern "C" void kernel_launch(void* const* d_in, const int* in_sizes, int n_in,
                              void* d_out, int out_size, void* d_ws, size_t ws_size,
                              hipStream_t stream)
{
    const float* h        = (const float*)d_in[0];
    const int*   pos_src  = (const int*)d_in[1];
    const int*   pos_dst  = (const int*)d_in[2];
    const int*   neg_src  = (const int*)d_in[3];
    const int*   neg_dst  = (const int*)d_in[4];
    const float* emb      = (const float*)d_in[5];
    const float* W_pos    = (const float*)d_in[6];
    const float* b_pos    = (const float*)d_in[7];
    const float* W_neg    = (const float*)d_in[8];
    const float* b_neg    = (const float*)d_in[9];
    const float* W_self   = (const float*)d_in[10];
    const float* b_self   = (const float*)d_in[11];
    const float* w_pos_b  = (const float*)d_in[12];
    const float* W_pos_u  = (const float*)d_in[13];
    const float* alpha_p  = (const float*)d_in[14];
    const float* w_neg_b  = (const float*)d_in[15];
    const float* W_neg_u  = (const float*)d_in[16];
    const float* alpha_n  = (const float*)d_in[17];
    float* out = (float*)d_out;

    const int n_nodes = in_sizes[0] / IN_DIM;   // 100000
    const int E       = in_sizes[1];            // 500000

    // Workspace layout (all 4B types; Hbuf aligned up to 16B).
    float* ws     = (float*)d_ws;
    float* wpos   = ws;                          // [E]
    float* wneg   = wpos + E;                    // [E]
    int*   counts = (int*)(wneg + E);            // [N]
    int*   offs   = counts + n_nodes;            // [N+1]
    int*   cur    = offs + n_nodes + 1;          // [N]
    int*   bsum   = cur + n_nodes;               // [128]
    int*   esrc   = bsum + 128;                  // [E]
    float* ew     = (float*)(esrc + E);          // [E]
    float* Hbuf   = (float*)(((uintptr_t)(ew + E) + 15) & ~(uintptr_t)15);
    float* Ubuf   = Hbuf;                        // overlaps (disjoint lifetime)

    const dim3 blk(256);
    const dim3 gU((n_nodes + 63) / 64, EMBED / 64);
    const dim3 gH((n_nodes + 63) / 64, HIDDEN / 64);
    const dim3 gE((E + 3) / 4);                  // wave-per-edge
    const dim3 gEt((E + 255) / 256);             // thread-per-edge
    const dim3 gN((n_nodes + 255) / 256);        // thread-per-node
    const dim3 gW((n_nodes + 3) / 4);            // wave-per-node
    const int  nb = (n_nodes + 1023) / 1024;     // scan blocks (98)

    // --- Phase 1: edge weights (U overlaps Hbuf) ---
    gemm_nn<<<gU, blk, 0, stream>>>(emb, W_pos_u, Ubuf, n_nodes, EMBED, EMBED);
    edge_weight<<<gE, blk, 0, stream>>>(emb, Ubuf, w_pos_b, alpha_p,
                                        pos_src, pos_dst, wpos, E);
    gemm_nn<<<gU, blk, 0, stream>>>(emb, W_neg_u, Ubuf, n_nodes, EMBED, EMBED);
    edge_weight<<<gE, blk, 0, stream>>>(emb, Ubuf, w_neg_b, alpha_n,
                                        neg_src, neg_dst, wneg, E);

    // --- Phase 2: self message directly into out ---
    gemm_bt<<<gH, blk, 0, stream>>>(h, W_self, b_self, out, n_nodes, HIDDEN, IN_DIM);

    // --- Phase 3: pos — CSR build, H GEMM, gather ---
    zero_int<<<gN, blk, 0, stream>>>(counts, n_nodes);
    hist<<<gEt, blk, 0, stream>>>(pos_dst, counts, E);
    scan1<<<nb, blk, 0, stream>>>(counts, offs, bsum, n_nodes);
    scan2<<<1, 128, 0, stream>>>(bsum, nb);
    scan3<<<gN, blk, 0, stream>>>(offs, cur, bsum, n_nodes, E);
    place<<<gEt, blk, 0, stream>>>(pos_src, pos_dst, wpos, cur, esrc, ew, E);
    gemm_bt<<<gH, blk, 0, stream>>>(h, W_pos, b_pos, Hbuf, n_nodes, HIDDEN, IN_DIM);
    gather<false><<<gW, blk, 0, stream>>>(Hbuf, offs, esrc, ew, out, n_nodes);

    // --- Phase 4: neg — CSR build (reuse buffers), H GEMM, gather + ReLU ---
    zero_int<<<gN, blk, 0, stream>>>(counts, n_nodes);
    hist<<<gEt, blk, 0, stream>>>(neg_dst, counts, E);
    scan1<<<nb, blk, 0, stream>>>(counts, offs, bsum, n_nodes);
    scan2<<<1, 128, 0, stream>>>(bsum, nb);
    scan3<<<gN, blk, 0, stream>>>(offs, cur, bsum, n_nodes, E);
    place<<<gEt, blk, 0, stream>>>(neg_src, neg_dst, wneg, cur, esrc, ew, E);
    gemm_bt<<<gH, blk, 0, stream>>>(h, W_neg, b_neg, Hbuf, n_nodes, HIDDEN, IN_DIM);
    gather<true><<<gW, blk, 0, stream>>>(Hbuf, offs, esrc, ew, out, n_nodes);
}